// Round 2
// baseline (5395.271 us; speedup 1.0000x reference)
//
#include <hip/hip_runtime.h>
#include <hip/hip_bf16.h>

// Symmetric contraction (MACE-style), B=2048, C=256, I=9, E=10. fp32 only:
// measured fp32-vs-np absmax is 0.5 vs threshold 7.24 -> cancellation forbids
// bf16/fp16 MFMA (eps ratio would put error >> threshold). Roofline: fp32 VALU.
//
// Round-2 structure: 4 passes (scalar, v0, v1, v2). Per pass, the symmetrized
// U table slice (~21.9 KB) is staged into LDS; all 64 lanes read the same row
// address -> broadcast, conflict-free. Wy slice lives in registers. x column
// in LDS (own column only -> no barrier). VGPR target <=128 -> 4 waves/SIMD.

#define NB 2048
#define NC 256
#define NI 9
#define NE 10

#define N_TRI 165   // C(9+2,3) sorted triples
#define N_PAIR 45   // C(9+1,2) sorted pairs

// pass 0 (scalar): triple rows 24 floats (23 used), pair rows 4 (3 used), 9 singles
// passes 1..3 (vector a): triple rows 32 (30 used), pair rows 4, 9 singles
#define P0_TRI_F4 6
#define PV_TRI_F4 8
#define P0SZ 4152   // 165*24 + 45*4 + 9 = 4149, pad to /4
#define PVSZ 5472   // 165*32 + 45*4 + 9 = 5469, pad to /4
// tab total = 4152 + 3*5472 = 20568 floats (82.3 KB) in d_ws

__global__ __launch_bounds__(256) void sc_prep(
    const float* __restrict__ U1_s, const float* __restrict__ U2_s,
    const float* __restrict__ U3_s, const float* __restrict__ U1_v,
    const float* __restrict__ U2_v, const float* __restrict__ U3_v,
    float* __restrict__ tab)
{
    const int tid = threadIdx.x;
    if (tid < N_TRI) {
        int m = tid, ii = 0, jj = 0, kk = 0, cnt = 0;
        for (int i = 0; i < NI; i++)
            for (int j = i; j < NI; j++)
                for (int k = j; k < NI; k++) {
                    if (cnt == m) { ii = i; jj = j; kk = k; }
                    cnt++;
                }
        int P[6][3]; int np;
        if (ii == jj && jj == kk) {
            np = 1;
            P[0][0] = ii; P[0][1] = ii; P[0][2] = ii;
        } else if (ii == jj) {
            np = 3;
            P[0][0] = ii; P[0][1] = ii; P[0][2] = kk;
            P[1][0] = ii; P[1][1] = kk; P[1][2] = ii;
            P[2][0] = kk; P[2][1] = ii; P[2][2] = ii;
        } else if (jj == kk) {
            np = 3;
            P[0][0] = ii; P[0][1] = jj; P[0][2] = jj;
            P[1][0] = jj; P[1][1] = ii; P[1][2] = jj;
            P[2][0] = jj; P[2][1] = jj; P[2][2] = ii;
        } else {
            np = 6;
            P[0][0] = ii; P[0][1] = jj; P[0][2] = kk;
            P[1][0] = ii; P[1][1] = kk; P[1][2] = jj;
            P[2][0] = jj; P[2][1] = ii; P[2][2] = kk;
            P[3][0] = jj; P[3][1] = kk; P[3][2] = ii;
            P[4][0] = kk; P[4][1] = ii; P[4][2] = jj;
            P[5][0] = kk; P[5][1] = jj; P[5][2] = ii;
        }
        // pass 0: scalar channel
        float* row0 = tab + m * 24;
        for (int t = 0; t < 23; t++) {
            float s = 0.f;
            for (int p = 0; p < np; p++)
                s += U3_s[((P[p][0] * NI + P[p][1]) * NI + P[p][2]) * 23 + t];
            row0[t] = s;
        }
        row0[23] = 0.f;
        // passes 1..3: vector channels
        for (int a = 0; a < 3; a++) {
            float* row = tab + P0SZ + a * PVSZ + m * 32;
            for (int t = 0; t < 30; t++) {
                float s = 0.f;
                for (int p = 0; p < np; p++)
                    s += U3_v[(((a * NI + P[p][0]) * NI + P[p][1]) * NI + P[p][2]) * 30 + t];
                row[t] = s;
            }
            row[30] = 0.f; row[31] = 0.f;
        }
    } else if (tid < N_TRI + N_PAIR) {
        int m = tid - N_TRI, ii = 0, jj = 0, cnt = 0;
        for (int i = 0; i < NI; i++)
            for (int j = i; j < NI; j++) {
                if (cnt == m) { ii = i; jj = j; }
                cnt++;
            }
        float* r0 = tab + N_TRI * 24 + m * 4;
        for (int t = 0; t < 3; t++) {
            float s = U2_s[(ii * NI + jj) * 3 + t];
            if (ii != jj) s += U2_s[(jj * NI + ii) * 3 + t];
            r0[t] = s;
        }
        r0[3] = 0.f;
        for (int a = 0; a < 3; a++) {
            float* r = tab + P0SZ + a * PVSZ + N_TRI * 32 + m * 4;
            for (int t = 0; t < 4; t++) {
                float s = U2_v[((a * NI + ii) * NI + jj) * 4 + t];
                if (ii != jj) s += U2_v[((a * NI + jj) * NI + ii) * 4 + t];
                r[t] = s;
            }
        }
    } else if (tid < N_TRI + N_PAIR + NI) {
        int i = tid - (N_TRI + N_PAIR);
        tab[N_TRI * 24 + N_PAIR * 4 + i] = U1_s[i];
        for (int a = 0; a < 3; a++)
            tab[P0SZ + a * PVSZ + N_TRI * 32 + N_PAIR * 4 + i] = U1_v[a * NI + i];
    }
}

// One pass: triples + pairs + singles against one wy slice.
// K4 = float4s per triple row (6 for scalar pass, 8 for vector passes).
template <int K4>
__device__ __forceinline__ float do_pass(
    const float* __restrict__ lds, const float (&wy3)[K4 * 4],
    const float (&wy2)[4], float wy1, const float* __restrict__ xsc)
{
    const float4* __restrict__ tri  = (const float4*)lds;
    const float4* __restrict__ pair = (const float4*)(lds + N_TRI * K4 * 4);
    const float*  __restrict__ sing = lds + N_TRI * K4 * 4 + N_PAIR * 4;

    float acc = 0.f;
    const float4* r = tri;
    for (int i = 0; i < NI; i++) {
        float xi = xsc[i * NC];
        for (int j = i; j < NI; j++) {
            float xij = xi * xsc[j * NC];
            for (int k = j; k < NI; k++) {
                float phi = xij * xsc[k * NC];
                float s0 = 0.f, s1 = 0.f, s2 = 0.f, s3 = 0.f;
                #pragma unroll
                for (int q = 0; q < K4; q++) {
                    float4 v = r[q];
                    s0 = fmaf(v.x, wy3[4 * q + 0], s0);
                    s1 = fmaf(v.y, wy3[4 * q + 1], s1);
                    s2 = fmaf(v.z, wy3[4 * q + 2], s2);
                    s3 = fmaf(v.w, wy3[4 * q + 3], s3);
                }
                acc = fmaf(phi, (s0 + s1) + (s2 + s3), acc);
                r += K4;
            }
        }
    }
    const float4* rp = pair;
    for (int i = 0; i < NI; i++) {
        float xi = xsc[i * NC];
        for (int j = i; j < NI; j++) {
            float phi = xi * xsc[j * NC];
            float4 v = *rp++;
            acc = fmaf(phi, fmaf(v.x, wy2[0], fmaf(v.y, wy2[1],
                       fmaf(v.z, wy2[2], v.w * wy2[3]))), acc);
        }
    }
    float sv = 0.f;
    #pragma unroll
    for (int i = 0; i < NI; i++) sv = fmaf(xsc[i * NC], sing[i], sv);
    acc = fmaf(wy1, sv, acc);
    return acc;
}

__device__ __forceinline__ void stage(float4* __restrict__ dst,
                                      const float4* __restrict__ src,
                                      int n4, int tid)
{
    for (int idx = tid; idx < n4; idx += NC) dst[idx] = src[idx];
}

__global__ __launch_bounds__(256, 4) void sc_main(
    const float* __restrict__ x, const float* __restrict__ y,
    const float* __restrict__ W1_s, const float* __restrict__ W2_s,
    const float* __restrict__ W3_s, const float* __restrict__ W1_v,
    const float* __restrict__ W2_v, const float* __restrict__ W3_v,
    const float* __restrict__ tab, float* __restrict__ out)
{
    __shared__ float4 ldsbuf4[PVSZ / 4];   // 21.9 KB, reused each pass
    __shared__ float xs[NI][NC];           // 9.2 KB
    float* ldsb = (float*)ldsbuf4;

    const int b = blockIdx.x;
    const int c = threadIdx.x;
    const float* xsc = &xs[0][c];

    // stage pass-0 table first so loads are in flight during Wy compute
    stage(ldsbuf4, (const float4*)tab, P0SZ / 4, c);

    {
        const float* xp = x + ((size_t)b * NC + c) * NI;
        #pragma unroll
        for (int i = 0; i < NI; i++) xs[i][c] = xp[i];  // own column only
    }

    float yr[NE];
    #pragma unroll
    for (int e = 0; e < NE; e++) yr[e] = y[b * NE + e];

    // ---- scalar-channel Wy slice ----
    float wy3s[24], wy2s[4], wy1s;
    #pragma unroll
    for (int t = 0; t < 23; t++) {
        float s = 0.f;
        #pragma unroll
        for (int e = 0; e < NE; e++) s = fmaf(yr[e], W3_s[(e * 23 + t) * NC + c], s);
        wy3s[t] = s;
    }
    wy3s[23] = 0.f;
    #pragma unroll
    for (int t = 0; t < 3; t++) {
        float s = 0.f;
        #pragma unroll
        for (int e = 0; e < NE; e++) s = fmaf(yr[e], W2_s[(e * 3 + t) * NC + c], s);
        wy2s[t] = s;
    }
    wy2s[3] = 0.f;
    {
        float s = 0.f;
        #pragma unroll
        for (int e = 0; e < NE; e++) s = fmaf(yr[e], W1_s[e * NC + c], s);
        wy1s = s;
    }

    __syncthreads();   // pass-0 table staged
    float accs = do_pass<P0_TRI_F4>(ldsb, wy3s, wy2s, wy1s, xsc);

    // ---- vector-channel Wy slice (shared across a) ----
    float wy3v[32], wy2v[4], wy1v;
    #pragma unroll
    for (int t = 0; t < 30; t++) {
        float s = 0.f;
        #pragma unroll
        for (int e = 0; e < NE; e++) s = fmaf(yr[e], W3_v[(e * 30 + t) * NC + c], s);
        wy3v[t] = s;
    }
    wy3v[30] = 0.f; wy3v[31] = 0.f;
    #pragma unroll
    for (int t = 0; t < 4; t++) {
        float s = 0.f;
        #pragma unroll
        for (int e = 0; e < NE; e++) s = fmaf(yr[e], W2_v[(e * 4 + t) * NC + c], s);
        wy2v[t] = s;
    }
    {
        float s = 0.f;
        #pragma unroll
        for (int e = 0; e < NE; e++) s = fmaf(yr[e], W1_v[e * NC + c], s);
        wy1v = s;
    }

    float accv[3];
    #pragma unroll
    for (int a = 0; a < 3; a++) {
        __syncthreads();   // everyone done with previous slice
        stage(ldsbuf4, (const float4*)(tab + P0SZ + a * PVSZ), PVSZ / 4, c);
        __syncthreads();   // slice ready
        accv[a] = do_pass<PV_TRI_F4>(ldsb, wy3v, wy2v, wy1v, xsc);
    }

    float* ob = out + (size_t)b * (4 * NC);
    ob[c] = accs;
    ob[NC + 3 * c + 0] = accv[0];
    ob[NC + 3 * c + 1] = accv[1];
    ob[NC + 3 * c + 2] = accv[2];
}

extern "C" void kernel_launch(void* const* d_in, const int* in_sizes, int n_in,
                              void* d_out, int out_size, void* d_ws, size_t ws_size,
                              hipStream_t stream) {
    const float* x    = (const float*)d_in[0];
    const float* y    = (const float*)d_in[1];
    const float* U1_s = (const float*)d_in[2];
    const float* U2_s = (const float*)d_in[3];
    const float* U3_s = (const float*)d_in[4];
    const float* U1_v = (const float*)d_in[5];
    const float* U2_v = (const float*)d_in[6];
    const float* U3_v = (const float*)d_in[7];
    const float* W1_s = (const float*)d_in[8];
    const float* W2_s = (const float*)d_in[9];
    const float* W3_s = (const float*)d_in[10];
    const float* W1_v = (const float*)d_in[11];
    const float* W2_v = (const float*)d_in[12];
    const float* W3_v = (const float*)d_in[13];
    float* out = (float*)d_out;
    float* tab = (float*)d_ws;   // 82.3 KB, rebuilt every call

    sc_prep<<<1, 256, 0, stream>>>(U1_s, U2_s, U3_s, U1_v, U2_v, U3_v, tab);
    sc_main<<<NB, NC, 0, stream>>>(x, y, W1_s, W2_s, W3_s, W1_v, W2_v, W3_v,
                                   tab, out);
}

// Round 3
// 524.482 us; speedup vs baseline: 10.2869x; 10.2869x over previous
//
#include <hip/hip_runtime.h>
#include <hip/hip_bf16.h>

// Symmetric contraction (MACE-style), B=2048, C=256, I=9, E=10. fp32 only
// (measured fp32 absmax 0.5 vs threshold 7.24; bf16/MFMA numerically dead).
//
// Round-3: e-contraction folded into a precomputed table
//   T[e, m, c, ch] = sum_t Sym_ch[m,t] * W_ch[e,t,c]   (ch = {s, v0, v1, v2})
// so the main kernel computes
//   out[b,c,ch] = sum_e sum_m y[b,e] * phi_m(x[b,c,:]) * T[e,m,c,ch]
// with per-lane coalesced float4 T loads (lane = c), 4 b's per thread to
// amortize each load over 20 FMAs. ~9.5k FMA/item vs 20.3k direct.
// Round-2 lesson: NO waves/EU launch-bound cap (caused 11 GB scratch spill).

#define NB 2048
#define NC 256
#define NI 9
#define NE 10

#define N_TRI 165   // C(9+2,3) sorted triples
#define N_PAIR 45   // C(9+1,2) sorted pairs

// ---- workspace layout (float offsets) ----
#define S3S 0                       // Sym3_s [165][23]
#define S3V 3795                    // Sym3_v [3][165][30]
#define S2S 18645                   // Sym2_s [45][3]
#define S2V 18780                   // Sym2_v [3][45][4]
#define S1S 19320                   // Sym1_s [9]
#define S1V 19329                   // Sym1_v [3][9]
#define T3O 19360                   // T3 [10][165][256][4]  (16B-aligned)
#define T2O (T3O + 10*165*256*4)    // T2 [10][45][256][4]
#define T1O (T2O + 10*45*256*4)     // T1 [10][9][256][4]
// total = T1O + 10*9*256*4 = 2,261,920 floats = 9.05 MB

#define BTILE 4      // b's per thread
#define CTILE 64     // c's per block (one wave-width)

// ---------------- prep 1: symmetrize U -> Sym tables ----------------
__global__ __launch_bounds__(256) void sc_prep1(
    const float* __restrict__ U1_s, const float* __restrict__ U2_s,
    const float* __restrict__ U3_s, const float* __restrict__ U1_v,
    const float* __restrict__ U2_v, const float* __restrict__ U3_v,
    float* __restrict__ ws)
{
    const int tid = threadIdx.x;
    if (tid < N_TRI) {
        int m = tid, ii = 0, jj = 0, kk = 0, cnt = 0;
        for (int i = 0; i < NI; i++)
            for (int j = i; j < NI; j++)
                for (int k = j; k < NI; k++) {
                    if (cnt == m) { ii = i; jj = j; kk = k; }
                    cnt++;
                }
        int P[6][3]; int np;
        if (ii == jj && jj == kk) {
            np = 1;
            P[0][0] = ii; P[0][1] = ii; P[0][2] = ii;
        } else if (ii == jj) {
            np = 3;
            P[0][0] = ii; P[0][1] = ii; P[0][2] = kk;
            P[1][0] = ii; P[1][1] = kk; P[1][2] = ii;
            P[2][0] = kk; P[2][1] = ii; P[2][2] = ii;
        } else if (jj == kk) {
            np = 3;
            P[0][0] = ii; P[0][1] = jj; P[0][2] = jj;
            P[1][0] = jj; P[1][1] = ii; P[1][2] = jj;
            P[2][0] = jj; P[2][1] = jj; P[2][2] = ii;
        } else {
            np = 6;
            P[0][0] = ii; P[0][1] = jj; P[0][2] = kk;
            P[1][0] = ii; P[1][1] = kk; P[1][2] = jj;
            P[2][0] = jj; P[2][1] = ii; P[2][2] = kk;
            P[3][0] = jj; P[3][1] = kk; P[3][2] = ii;
            P[4][0] = kk; P[4][1] = ii; P[4][2] = jj;
            P[5][0] = kk; P[5][1] = jj; P[5][2] = ii;
        }
        for (int t = 0; t < 23; t++) {
            float s = 0.f;
            for (int p = 0; p < np; p++)
                s += U3_s[((P[p][0] * NI + P[p][1]) * NI + P[p][2]) * 23 + t];
            ws[S3S + m * 23 + t] = s;
        }
        for (int a = 0; a < 3; a++)
            for (int t = 0; t < 30; t++) {
                float s = 0.f;
                for (int p = 0; p < np; p++)
                    s += U3_v[(((a * NI + P[p][0]) * NI + P[p][1]) * NI + P[p][2]) * 30 + t];
                ws[S3V + (a * N_TRI + m) * 30 + t] = s;
            }
    } else if (tid < N_TRI + N_PAIR) {
        int m = tid - N_TRI, ii = 0, jj = 0, cnt = 0;
        for (int i = 0; i < NI; i++)
            for (int j = i; j < NI; j++) {
                if (cnt == m) { ii = i; jj = j; }
                cnt++;
            }
        for (int t = 0; t < 3; t++) {
            float s = U2_s[(ii * NI + jj) * 3 + t];
            if (ii != jj) s += U2_s[(jj * NI + ii) * 3 + t];
            ws[S2S + m * 3 + t] = s;
        }
        for (int a = 0; a < 3; a++)
            for (int t = 0; t < 4; t++) {
                float s = U2_v[((a * NI + ii) * NI + jj) * 4 + t];
                if (ii != jj) s += U2_v[((a * NI + jj) * NI + ii) * 4 + t];
                ws[S2V + (a * N_PAIR + m) * 4 + t] = s;
            }
    } else if (tid < N_TRI + N_PAIR + NI) {
        int i = tid - (N_TRI + N_PAIR);
        ws[S1S + i] = U1_s[i];
        for (int a = 0; a < 3; a++) ws[S1V + a * NI + i] = U1_v[a * NI + i];
    }
}

// ---------------- prep 2: T[e,m,c,ch] = Sym x W ----------------
// grid: (219 rows, 10 e) x 256 threads (c)
__global__ __launch_bounds__(256) void sc_prep2(
    const float* __restrict__ W1_s, const float* __restrict__ W2_s,
    const float* __restrict__ W3_s, const float* __restrict__ W1_v,
    const float* __restrict__ W2_v, const float* __restrict__ W3_v,
    float* __restrict__ ws)
{
    const int m = blockIdx.x;   // 0..218
    const int e = blockIdx.y;   // 0..9
    const int c = threadIdx.x;  // 0..255
    float s = 0.f, v0 = 0.f, v1 = 0.f, v2 = 0.f;
    float4* dst;
    if (m < N_TRI) {
        #pragma unroll
        for (int t = 0; t < 23; t++)
            s = fmaf(ws[S3S + m * 23 + t], W3_s[(e * 23 + t) * NC + c], s);
        float wv[30];
        #pragma unroll
        for (int t = 0; t < 30; t++) wv[t] = W3_v[(e * 30 + t) * NC + c];
        #pragma unroll
        for (int t = 0; t < 30; t++) {
            v0 = fmaf(ws[S3V + (0 * N_TRI + m) * 30 + t], wv[t], v0);
            v1 = fmaf(ws[S3V + (1 * N_TRI + m) * 30 + t], wv[t], v1);
            v2 = fmaf(ws[S3V + (2 * N_TRI + m) * 30 + t], wv[t], v2);
        }
        dst = (float4*)(ws + T3O) + (e * N_TRI + m) * NC + c;
    } else if (m < N_TRI + N_PAIR) {
        const int m2 = m - N_TRI;
        #pragma unroll
        for (int t = 0; t < 3; t++)
            s = fmaf(ws[S2S + m2 * 3 + t], W2_s[(e * 3 + t) * NC + c], s);
        #pragma unroll
        for (int t = 0; t < 4; t++) {
            float wv = W2_v[(e * 4 + t) * NC + c];
            v0 = fmaf(ws[S2V + (0 * N_PAIR + m2) * 4 + t], wv, v0);
            v1 = fmaf(ws[S2V + (1 * N_PAIR + m2) * 4 + t], wv, v1);
            v2 = fmaf(ws[S2V + (2 * N_PAIR + m2) * 4 + t], wv, v2);
        }
        dst = (float4*)(ws + T2O) + (e * N_PAIR + m2) * NC + c;
    } else {
        const int i = m - N_TRI - N_PAIR;
        float ws1 = W1_s[e * NC + c], wv1 = W1_v[e * NC + c];
        s  = ws[S1S + i] * ws1;
        v0 = ws[S1V + 0 * NI + i] * wv1;
        v1 = ws[S1V + 1 * NI + i] * wv1;
        v2 = ws[S1V + 2 * NI + i] * wv1;
        dst = (float4*)(ws + T1O) + (e * NI + i) * NC + c;
    }
    *dst = make_float4(s, v0, v1, v2);
}

// ---------------- main ----------------
// block = 256 threads = (64 c-lanes) x (4 b-subgroups); each thread: 4 b's.
// grid = (2048/16 b-tiles, 256/64 c-tiles) = (128, 4).
__global__ void sc_main(
    const float* __restrict__ x, const float* __restrict__ y,
    const float* __restrict__ ws, float* __restrict__ out)
{
    const int tx = threadIdx.x & 63;
    const int ty = threadIdx.x >> 6;
    const int c  = (blockIdx.y << 6) + tx;
    const int b0 = (blockIdx.x << 4) + (ty << 2);

    // x in LDS for runtime i/j/k indexing; own-slot write/read -> no barrier.
    // addr (( (ty*9+i)*4 + n)*64 + tx): lanes consecutive -> conflict-free.
    __shared__ float xs[4][NI][BTILE][64];
    #pragma unroll
    for (int n = 0; n < BTILE; n++) {
        const float* xp = x + ((size_t)(b0 + n) * NC + c) * NI;
        #pragma unroll
        for (int i = 0; i < NI; i++) xs[ty][i][n][tx] = xp[i];
    }
    const float* xb = &xs[ty][0][0][tx];   // xb[(i*BTILE+n)*64]

    float w[NE][BTILE];
    #pragma unroll
    for (int n = 0; n < BTILE; n++) {
        const float* yp = y + (size_t)(b0 + n) * NE;
        #pragma unroll
        for (int e = 0; e < NE; e++) w[e][n] = yp[e];
    }

    float acc[BTILE][4];
    #pragma unroll
    for (int n = 0; n < BTILE; n++)
        #pragma unroll
        for (int h = 0; h < 4; h++) acc[n][h] = 0.f;

    const float4* __restrict__ T3p = (const float4*)(ws + T3O) + c;
    const float4* __restrict__ T2p = (const float4*)(ws + T2O) + c;
    const float4* __restrict__ T1p = (const float4*)(ws + T1O) + c;

    // ---- correlation 3: 165 sorted triples ----
    {
        int m = 0;
        for (int i = 0; i < NI; i++) {
            float xi[BTILE];
            #pragma unroll
            for (int n = 0; n < BTILE; n++) xi[n] = xb[(i * BTILE + n) * 64];
            for (int j = i; j < NI; j++) {
                float xij[BTILE];
                #pragma unroll
                for (int n = 0; n < BTILE; n++)
                    xij[n] = xi[n] * xb[(j * BTILE + n) * 64];
                for (int k = j; k < NI; k++, m++) {
                    float phi[BTILE];
                    #pragma unroll
                    for (int n = 0; n < BTILE; n++)
                        phi[n] = xij[n] * xb[(k * BTILE + n) * 64];
                    const float4* Tm = T3p + (size_t)m * NC;
                    #pragma unroll
                    for (int e = 0; e < NE; e++) {
                        float4 t = Tm[e * N_TRI * NC];
                        #pragma unroll
                        for (int n = 0; n < BTILE; n++) {
                            float p = w[e][n] * phi[n];
                            acc[n][0] = fmaf(p, t.x, acc[n][0]);
                            acc[n][1] = fmaf(p, t.y, acc[n][1]);
                            acc[n][2] = fmaf(p, t.z, acc[n][2]);
                            acc[n][3] = fmaf(p, t.w, acc[n][3]);
                        }
                    }
                }
            }
        }
    }

    // ---- correlation 2: 45 sorted pairs ----
    {
        int m = 0;
        for (int i = 0; i < NI; i++) {
            float xi[BTILE];
            #pragma unroll
            for (int n = 0; n < BTILE; n++) xi[n] = xb[(i * BTILE + n) * 64];
            for (int j = i; j < NI; j++, m++) {
                float phi[BTILE];
                #pragma unroll
                for (int n = 0; n < BTILE; n++)
                    phi[n] = xi[n] * xb[(j * BTILE + n) * 64];
                const float4* Tm = T2p + (size_t)m * NC;
                #pragma unroll
                for (int e = 0; e < NE; e++) {
                    float4 t = Tm[e * N_PAIR * NC];
                    #pragma unroll
                    for (int n = 0; n < BTILE; n++) {
                        float p = w[e][n] * phi[n];
                        acc[n][0] = fmaf(p, t.x, acc[n][0]);
                        acc[n][1] = fmaf(p, t.y, acc[n][1]);
                        acc[n][2] = fmaf(p, t.z, acc[n][2]);
                        acc[n][3] = fmaf(p, t.w, acc[n][3]);
                    }
                }
            }
        }
    }

    // ---- correlation 1: 9 singles ----
    for (int i = 0; i < NI; i++) {
        float phi[BTILE];
        #pragma unroll
        for (int n = 0; n < BTILE; n++) phi[n] = xb[(i * BTILE + n) * 64];
        const float4* Tm = T1p + (size_t)i * NC;
        #pragma unroll
        for (int e = 0; e < NE; e++) {
            float4 t = Tm[e * NI * NC];
            #pragma unroll
            for (int n = 0; n < BTILE; n++) {
                float p = w[e][n] * phi[n];
                acc[n][0] = fmaf(p, t.x, acc[n][0]);
                acc[n][1] = fmaf(p, t.y, acc[n][1]);
                acc[n][2] = fmaf(p, t.z, acc[n][2]);
                acc[n][3] = fmaf(p, t.w, acc[n][3]);
            }
        }
    }

    // out row: [ out_s (256) | out_v (c,3) ]
    #pragma unroll
    for (int n = 0; n < BTILE; n++) {
        float* ob = out + (size_t)(b0 + n) * (4 * NC);
        ob[c] = acc[n][0];
        ob[NC + 3 * c + 0] = acc[n][1];
        ob[NC + 3 * c + 1] = acc[n][2];
        ob[NC + 3 * c + 2] = acc[n][3];
    }
}

extern "C" void kernel_launch(void* const* d_in, const int* in_sizes, int n_in,
                              void* d_out, int out_size, void* d_ws, size_t ws_size,
                              hipStream_t stream) {
    const float* x    = (const float*)d_in[0];
    const float* y    = (const float*)d_in[1];
    const float* U1_s = (const float*)d_in[2];
    const float* U2_s = (const float*)d_in[3];
    const float* U3_s = (const float*)d_in[4];
    const float* U1_v = (const float*)d_in[5];
    const float* U2_v = (const float*)d_in[6];
    const float* U3_v = (const float*)d_in[7];
    const float* W1_s = (const float*)d_in[8];
    const float* W2_s = (const float*)d_in[9];
    const float* W3_s = (const float*)d_in[10];
    const float* W1_v = (const float*)d_in[11];
    const float* W2_v = (const float*)d_in[12];
    const float* W3_v = (const float*)d_in[13];
    float* out = (float*)d_out;
    float* ws  = (float*)d_ws;   // needs ~9.05 MB; rebuilt every call

    sc_prep1<<<1, 256, 0, stream>>>(U1_s, U2_s, U3_s, U1_v, U2_v, U3_v, ws);
    sc_prep2<<<dim3(N_TRI + N_PAIR + NI, NE), 256, 0, stream>>>(
        W1_s, W2_s, W3_s, W1_v, W2_v, W3_v, ws);
    sc_main<<<dim3(NB / (4 * BTILE), NC / CTILE), 256, 0, stream>>>(x, y, ws, out);
}

// Round 4
// 305.735 us; speedup vs baseline: 17.6469x; 1.7155x over previous
//
#include <hip/hip_runtime.h>
#include <hip/hip_bf16.h>

// Symmetric contraction (MACE-style), B=2048, C=256, I=9, E=10. fp32 only
// (fp32 absmax 0.5 vs threshold 7.24; bf16/MFMA numerically dead).
//
// Round-4:
//  * prep fused into ONE parallel kernel (round-3's serial prep1 cost ~200us)
//  * T[m][e][c][4ch]: out[b,c,ch] = sum_m sum_e y[b,e] phi_m(x[b,c]) T[m,e,c,ch]
//  * BTILE=8 b's/thread -> each 16B T load feeds 40 FMAs; T L2 traffic 2.3 GB
//  * y weights are wave-uniform (lanes=c) -> forced to SGPRs via readfirstlane
//  * explicit register double-buffer over m hides L2 latency at 1 wave/SIMD
//  * XCD swizzle: c_tile = (bid&7)>>1 -> per-XCD T slice 2.24 MB < 4 MB L2
// Round-2 lesson: no waves/EU launch-bounds cap (spill disaster).

#define NB 2048
#define NC 256
#define NI 9
#define NE 10

#define N_TRI 165
#define N_PAIR 45

// workspace float4 layout: T3 [165][10][256] | T2 [45][10][256] | T1 [9][10][256]
#define T3N (N_TRI * NE * NC)
#define T2N (N_PAIR * NE * NC)
#define T1N (NI * NE * NC)
// total float4s = 560,640 -> 8.97 MB

// ---------------- fused prep: Sym (in LDS) x W -> T ----------------
// grid (219, 10) x 256 threads. block = one (m-row, e).
__global__ __launch_bounds__(256) void sc_prep(
    const float* __restrict__ U1_s, const float* __restrict__ U2_s,
    const float* __restrict__ U3_s, const float* __restrict__ U1_v,
    const float* __restrict__ U2_v, const float* __restrict__ U3_v,
    const float* __restrict__ W1_s, const float* __restrict__ W2_s,
    const float* __restrict__ W3_s, const float* __restrict__ W1_v,
    const float* __restrict__ W2_v, const float* __restrict__ W3_v,
    float* __restrict__ ws)
{
    const int m = blockIdx.x;    // 0..218
    const int e = blockIdx.y;    // 0..9
    const int tid = threadIdx.x; // 0..255
    float4* __restrict__ T3 = (float4*)ws;
    float4* __restrict__ T2 = T3 + T3N;
    float4* __restrict__ T1 = T2 + T2N;

    __shared__ float sym[128];

    if (m < N_TRI) {
        if (tid < 113) {
            // decode sorted triple
            int ii = 0, jj = 0, kk = 0, cnt = 0;
            for (int i = 0; i < NI; i++)
                for (int j = i; j < NI; j++)
                    for (int k = j; k < NI; k++) {
                        if (cnt == m) { ii = i; jj = j; kk = k; }
                        cnt++;
                    }
            int P[6][3]; int np;
            if (ii == jj && jj == kk) {
                np = 1;
                P[0][0] = ii; P[0][1] = ii; P[0][2] = ii;
            } else if (ii == jj) {
                np = 3;
                P[0][0] = ii; P[0][1] = ii; P[0][2] = kk;
                P[1][0] = ii; P[1][1] = kk; P[1][2] = ii;
                P[2][0] = kk; P[2][1] = ii; P[2][2] = ii;
            } else if (jj == kk) {
                np = 3;
                P[0][0] = ii; P[0][1] = jj; P[0][2] = jj;
                P[1][0] = jj; P[1][1] = ii; P[1][2] = jj;
                P[2][0] = jj; P[2][1] = jj; P[2][2] = ii;
            } else {
                np = 6;
                P[0][0] = ii; P[0][1] = jj; P[0][2] = kk;
                P[1][0] = ii; P[1][1] = kk; P[1][2] = jj;
                P[2][0] = jj; P[2][1] = ii; P[2][2] = kk;
                P[3][0] = jj; P[3][1] = kk; P[3][2] = ii;
                P[4][0] = kk; P[4][1] = ii; P[4][2] = jj;
                P[5][0] = kk; P[5][1] = jj; P[5][2] = ii;
            }
            float s = 0.f;
            if (tid < 23) {
                for (int p = 0; p < np; p++)
                    s += U3_s[((P[p][0] * NI + P[p][1]) * NI + P[p][2]) * 23 + tid];
            } else {
                int a = (tid - 23) / 30, t = (tid - 23) % 30;
                for (int p = 0; p < np; p++)
                    s += U3_v[(((a * NI + P[p][0]) * NI + P[p][1]) * NI + P[p][2]) * 30 + t];
            }
            sym[tid] = s;
        }
        __syncthreads();
        const int c = tid;
        float s = 0.f, v0 = 0.f, v1 = 0.f, v2 = 0.f;
        #pragma unroll
        for (int t = 0; t < 23; t++)
            s = fmaf(sym[t], W3_s[(e * 23 + t) * NC + c], s);
        #pragma unroll
        for (int t = 0; t < 30; t++) {
            float wv = W3_v[(e * 30 + t) * NC + c];
            v0 = fmaf(sym[23 + t],      wv, v0);
            v1 = fmaf(sym[53 + t],      wv, v1);
            v2 = fmaf(sym[83 + t],      wv, v2);
        }
        T3[(m * NE + e) * NC + c] = make_float4(s, v0, v1, v2);
    } else if (m < N_TRI + N_PAIR) {
        const int mm = m - N_TRI;
        if (tid < 15) {
            int ii = 0, jj = 0, cnt = 0;
            for (int i = 0; i < NI; i++)
                for (int j = i; j < NI; j++) {
                    if (cnt == mm) { ii = i; jj = j; }
                    cnt++;
                }
            float s;
            if (tid < 3) {
                s = U2_s[(ii * NI + jj) * 3 + tid];
                if (ii != jj) s += U2_s[(jj * NI + ii) * 3 + tid];
            } else {
                int a = (tid - 3) / 4, t = (tid - 3) % 4;
                s = U2_v[((a * NI + ii) * NI + jj) * 4 + t];
                if (ii != jj) s += U2_v[((a * NI + jj) * NI + ii) * 4 + t];
            }
            sym[tid] = s;
        }
        __syncthreads();
        const int c = tid;
        float s = 0.f, v0 = 0.f, v1 = 0.f, v2 = 0.f;
        #pragma unroll
        for (int t = 0; t < 3; t++)
            s = fmaf(sym[t], W2_s[(e * 3 + t) * NC + c], s);
        #pragma unroll
        for (int t = 0; t < 4; t++) {
            float wv = W2_v[(e * 4 + t) * NC + c];
            v0 = fmaf(sym[3 + t],  wv, v0);
            v1 = fmaf(sym[7 + t],  wv, v1);
            v2 = fmaf(sym[11 + t], wv, v2);
        }
        T2[(mm * NE + e) * NC + c] = make_float4(s, v0, v1, v2);
    } else {
        const int i = m - N_TRI - N_PAIR;
        const int c = tid;
        float w1s = W1_s[e * NC + c], w1v = W1_v[e * NC + c];
        T1[(i * NE + e) * NC + c] = make_float4(
            U1_s[i] * w1s,
            U1_v[0 * NI + i] * w1v,
            U1_v[1 * NI + i] * w1v,
            U1_v[2 * NI + i] * w1v);
    }
}

// ---------------- main ----------------
// 512 blocks x 128 threads. wave = 64 c-lanes; 2 waves (ty) per block.
// Each thread: 8 b's x 1 c x 4 ch. XCD swizzle pins c_tile per XCD.
#define BT 8
__global__ __launch_bounds__(128) void sc_main(
    const float* __restrict__ x, const float* __restrict__ y,
    const float* __restrict__ ws, float* __restrict__ out)
{
    const int tid = threadIdx.x;
    const int tx  = tid & 63;
    const int tyu = __builtin_amdgcn_readfirstlane(tid >> 6);  // wave-uniform
    const int bid = blockIdx.x;
    const int xcd    = bid & 7;
    const int c_tile = xcd >> 1;                 // XCD pair owns one c-slice
    const int b_tile = ((bid >> 3) << 1) | (xcd & 1);
    const int c  = (c_tile << 6) + tx;
    const int b0 = (b_tile << 4) + (tyu << 3);   // uniform

    // x staging: own-slot (tyu, *, *, tx) -> no barrier. b32 reads conflict-free.
    __shared__ float xs[2][NI][BT][64];
    #pragma unroll
    for (int n = 0; n < BT; n++) {
        const float* xp = x + ((size_t)(b0 + n) * NC + c) * NI;
        #pragma unroll
        for (int i = 0; i < NI; i++) xs[tyu][i][n][tx] = xp[i];
    }

    // y weights: address fully uniform -> s_load -> SGPRs (saves ~80 VGPRs)
    float w[NE][BT];
    #pragma unroll
    for (int n = 0; n < BT; n++)
        #pragma unroll
        for (int e = 0; e < NE; e++) w[e][n] = y[(b0 + n) * NE + e];

    float acc[BT][4];
    #pragma unroll
    for (int n = 0; n < BT; n++)
        #pragma unroll
        for (int h = 0; h < 4; h++) acc[n][h] = 0.f;

    const float4* __restrict__ T3 = (const float4*)ws;
    const float4* __restrict__ T2 = T3 + T3N;
    const float4* __restrict__ T1 = T2 + T2N;

    // ---- triples: flat m-loop, register double-buffer over m ----
    {
        float4 tc[NE];
        #pragma unroll
        for (int e = 0; e < NE; e++) tc[e] = T3[e * NC + c];   // m = 0
        int i = 0, j = 0, k = 0;
        for (int m = 0; m < N_TRI; m++) {
            const int mn = (m == N_TRI - 1) ? m : m + 1;
            float4 tn[NE];
            #pragma unroll
            for (int e = 0; e < NE; e++) tn[e] = T3[(mn * NE + e) * NC + c];
            float phi[BT];
            #pragma unroll
            for (int n = 0; n < BT; n++)
                phi[n] = xs[tyu][i][n][tx] * xs[tyu][j][n][tx] * xs[tyu][k][n][tx];
            #pragma unroll
            for (int e = 0; e < NE; e++) {
                const float4 t = tc[e];
                #pragma unroll
                for (int n = 0; n < BT; n++) {
                    const float p = w[e][n] * phi[n];
                    acc[n][0] = fmaf(p, t.x, acc[n][0]);
                    acc[n][1] = fmaf(p, t.y, acc[n][1]);
                    acc[n][2] = fmaf(p, t.z, acc[n][2]);
                    acc[n][3] = fmaf(p, t.w, acc[n][3]);
                }
            }
            #pragma unroll
            for (int e = 0; e < NE; e++) tc[e] = tn[e];
            // advance sorted (i<=j<=k)
            k++;
            if (k == NI) { j++; if (j == NI) { i++; j = i; } k = j; }
        }
    }

    // ---- pairs: same pattern ----
    {
        float4 tc[NE];
        #pragma unroll
        for (int e = 0; e < NE; e++) tc[e] = T2[e * NC + c];   // m = 0
        int i = 0, j = 0;
        for (int m = 0; m < N_PAIR; m++) {
            const int mn = (m == N_PAIR - 1) ? m : m + 1;
            float4 tn[NE];
            #pragma unroll
            for (int e = 0; e < NE; e++) tn[e] = T2[(mn * NE + e) * NC + c];
            float phi[BT];
            #pragma unroll
            for (int n = 0; n < BT; n++)
                phi[n] = xs[tyu][i][n][tx] * xs[tyu][j][n][tx];
            #pragma unroll
            for (int e = 0; e < NE; e++) {
                const float4 t = tc[e];
                #pragma unroll
                for (int n = 0; n < BT; n++) {
                    const float p = w[e][n] * phi[n];
                    acc[n][0] = fmaf(p, t.x, acc[n][0]);
                    acc[n][1] = fmaf(p, t.y, acc[n][1]);
                    acc[n][2] = fmaf(p, t.z, acc[n][2]);
                    acc[n][3] = fmaf(p, t.w, acc[n][3]);
                }
            }
            #pragma unroll
            for (int e = 0; e < NE; e++) tc[e] = tn[e];
            j++;
            if (j == NI) { i++; j = i; }
        }
    }

    // ---- singles ----
    for (int i = 0; i < NI; i++) {
        float4 tc[NE];
        #pragma unroll
        for (int e = 0; e < NE; e++) tc[e] = T1[(i * NE + e) * NC + c];
        float phi[BT];
        #pragma unroll
        for (int n = 0; n < BT; n++) phi[n] = xs[tyu][i][n][tx];
        #pragma unroll
        for (int e = 0; e < NE; e++) {
            const float4 t = tc[e];
            #pragma unroll
            for (int n = 0; n < BT; n++) {
                const float p = w[e][n] * phi[n];
                acc[n][0] = fmaf(p, t.x, acc[n][0]);
                acc[n][1] = fmaf(p, t.y, acc[n][1]);
                acc[n][2] = fmaf(p, t.z, acc[n][2]);
                acc[n][3] = fmaf(p, t.w, acc[n][3]);
            }
        }
    }

    // out row: [ out_s (256) | out_v (3c+a) ]
    #pragma unroll
    for (int n = 0; n < BT; n++) {
        float* ob = out + (size_t)(b0 + n) * (4 * NC);
        ob[c] = acc[n][0];
        ob[NC + 3 * c + 0] = acc[n][1];
        ob[NC + 3 * c + 1] = acc[n][2];
        ob[NC + 3 * c + 2] = acc[n][3];
    }
}

extern "C" void kernel_launch(void* const* d_in, const int* in_sizes, int n_in,
                              void* d_out, int out_size, void* d_ws, size_t ws_size,
                              hipStream_t stream) {
    const float* x    = (const float*)d_in[0];
    const float* y    = (const float*)d_in[1];
    const float* U1_s = (const float*)d_in[2];
    const float* U2_s = (const float*)d_in[3];
    const float* U3_s = (const float*)d_in[4];
    const float* U1_v = (const float*)d_in[5];
    const float* U2_v = (const float*)d_in[6];
    const float* U3_v = (const float*)d_in[7];
    const float* W1_s = (const float*)d_in[8];
    const float* W2_s = (const float*)d_in[9];
    const float* W3_s = (const float*)d_in[10];
    const float* W1_v = (const float*)d_in[11];
    const float* W2_v = (const float*)d_in[12];
    const float* W3_v = (const float*)d_in[13];
    float* out = (float*)d_out;
    float* ws  = (float*)d_ws;   // 8.97 MB T table, rebuilt every call

    sc_prep<<<dim3(N_TRI + N_PAIR + NI, NE), 256, 0, stream>>>(
        U1_s, U2_s, U3_s, U1_v, U2_v, U3_v,
        W1_s, W2_s, W3_s, W1_v, W2_v, W3_v, ws);
    sc_main<<<NB / 16 * (NC / 64), 128, 0, stream>>>(x, y, ws, out);
}